// Round 12
// baseline (514.367 us; speedup 1.0000x reference)
//
#include <hip/hip_runtime.h>
#include <hip/hip_bf16.h>

// CostAttention on MI355X — round 12.
// R11 post-mortem: cross-block combine regressed 115->250 us. Device-scope
// __threadfence() for the partial handoff forces L2 writeback/invalidate on
// non-coherent per-XCD L2s -> K/V working set evicted continuously (WRITE_SIZE
// 6.4->29 MB, MfmaUtil 40->14%). Lesson: no global-memory combine on CDNA4.
// R12: same TLP target with ZERO cross-block traffic — 400 blocks x 512 thr
// (8 waves): block = one 64-row job, m-split over its 8 waves (25 chunks of
// 32 m each), combine fully in-block (8-phase barrier LDS accumulation).
// __launch_bounds__(512,4) (VGPR cap 128; R11's identical loop compiled to
// 112) -> 2 blocks/CU -> up to 4 waves/SIMD on doubly-loaded CUs.
// Keep: V-lo dropped (R11 absmax proof: still 2.441e-4), fixed-shift exp2
// softmax, P-hi-only RNE, ones-MFMA l, cross-iter K/V prefetch, R11 prep.
//
// ws layout: shorts [Qh][Ql][Kh][Kl][Vh], each SZ = 1,638,400 shorts (16.4MB).
//   Q/K chunk  ((b*400+mi)*2+c0)*512 + lane*8 : elem [r=16mi+l16][c=32c0+8qq+j]
//   V   chunk  (((b*100+i64)*8)+ct*2+mh)*512 + lane*8 : elem [c=16ct+l16][m=64i64+32mh+8qq+j]

#define NPIX 6400
#define SZ 1638400
#define SHIFT2 11.541560327111707f   // 8 * log2(e)

typedef float f32x4 __attribute__((ext_vector_type(4)));
typedef short bf16x8 __attribute__((ext_vector_type(8)));

#if defined(__has_builtin)
#if __has_builtin(__builtin_amdgcn_sched_barrier)
#define SCHED_FENCE() __builtin_amdgcn_sched_barrier(0)
#endif
#if __has_builtin(__builtin_amdgcn_exp2f)
#define EXP2(x) __builtin_amdgcn_exp2f(x)
#endif
#endif
#ifndef SCHED_FENCE
#define SCHED_FENCE()
#endif
#ifndef EXP2
#define EXP2(x) exp2f(x)
#endif

__device__ __forceinline__ void split2(float x, short& h, short& l) {
  unsigned xb = __float_as_uint(x);
  h = (short)(xb >> 16);
  float r = x - __uint_as_float(xb & 0xffff0000u);
  l = (short)(__float_as_uint(r) >> 16);
}

__device__ __forceinline__ short rne_bf16(float x) {
  unsigned u = __float_as_uint(x);
  return (short)((u + 0x7fffu + ((u >> 16) & 1u)) >> 16);
}

__device__ __forceinline__ unsigned pk2(float a, float b) {
  __hip_bfloat162 t = __float22bfloat162_rn(make_float2(a, b));
  unsigned r;
  __builtin_memcpy(&r, &t, 4);
  return r;
}

// ---------------- prep (R11, unchanged): stage -> LDS -> frag gather --------
// grid 1000: [0,400) K (b,m-tile) | [400,800) Q-proj (b,r-tile) | [800,1000) V
__global__ __launch_bounds__(256, 2) void prep(
    const float* __restrict__ query, const float* __restrict__ keys,
    const float* __restrict__ values, const float* __restrict__ Wq,
    const float* __restrict__ bq, short* __restrict__ ws)
{
  const int tid = threadIdx.x;
  const int w = tid >> 6;
  const int lane = tid & 63, l16 = lane & 15, qq = lane >> 4;
  short* Qh = ws;          short* Ql = ws + SZ;
  short* Kh = ws + 2 * SZ; short* Kl = ws + 3 * SZ;
  short* Vh = ws + 4 * SZ;
  const int x = blockIdx.x;

  __shared__ float T[64 * 65];

  if (x < 400) {                      // ---- K split (trunc hi/lo, 3-term S)
    const int b = x / 100, t64 = x % 100;
    const int m0 = t64 * 64;
    const float* kb = keys + (size_t)b * 64 * NPIX;
    {
      const int ch = tid >> 2, ml = (tid & 3) * 4;
      const float* src = kb + (size_t)ch * NPIX + m0 + ml;
      #pragma unroll
      for (int u = 0; u < 4; ++u)
        *(float4*)&T[ch * 65 + ml + 16 * u] = *(const float4*)(src + 16 * u);
    }
    __syncthreads();
    const int mi = t64 * 4 + w;
    #pragma unroll
    for (int c0 = 0; c0 < 2; ++c0) {
      float t[8];
      #pragma unroll
      for (int j = 0; j < 8; ++j)
        t[j] = T[(32 * c0 + 8 * qq + j) * 65 + 16 * w + l16];
      bf16x8 h8, l8;
      #pragma unroll
      for (int j = 0; j < 8; ++j) { short h, l; split2(t[j], h, l); h8[j] = h; l8[j] = l; }
      const int off = ((b * 400 + mi) * 2 + c0) * 512 + lane * 8;
      *(bf16x8*)(Kh + off) = h8;
      *(bf16x8*)(Kl + off) = l8;
    }
  } else if (x < 800) {               // ---- Q projection + trunc hi/lo split
    const int y = x - 400;
    const int b = y / 100, t64 = y % 100;
    const int r0 = t64 * 64;
    const float* qb = query + (size_t)b * 64 * NPIX;
    {
      const int ch = tid >> 2, ml = (tid & 3) * 4;
      const float* src = qb + (size_t)ch * NPIX + r0 + ml;
      #pragma unroll
      for (int u = 0; u < 4; ++u)
        *(float4*)&T[ch * 65 + ml + 16 * u] = *(const float4*)(src + 16 * u);
    }
    __syncthreads();
    const int mi = t64 * 4 + w;

    float acc[2][8];
    #pragma unroll
    for (int c0 = 0; c0 < 2; ++c0)
      #pragma unroll
      for (int j = 0; j < 8; ++j) acc[c0][j] = 0.f;

    for (int cin4 = 0; cin4 < 64; cin4 += 4) {
      float xv[4];
      #pragma unroll
      for (int u = 0; u < 4; ++u)
        xv[u] = T[(cin4 + u) * 65 + 16 * w + l16];
      #pragma unroll
      for (int c0 = 0; c0 < 2; ++c0)
        #pragma unroll
        for (int j = 0; j < 8; ++j) {
          const float4 wv = *(const float4*)&Wq[(32 * c0 + 8 * qq + j) * 64 + cin4];
          acc[c0][j] += wv.x * xv[0] + wv.y * xv[1] + wv.z * xv[2] + wv.w * xv[3];
        }
    }
    #pragma unroll
    for (int c0 = 0; c0 < 2; ++c0) {
      bf16x8 h8, l8;
      #pragma unroll
      for (int j = 0; j < 8; ++j) {
        // scale = (1/8)*log2(e): S in log2 domain -> raw exp2 in main
        float v = (acc[c0][j] + bq[32 * c0 + 8 * qq + j]) * 0.18033688011112042f;
        short h, l; split2(v, h, l);
        h8[j] = h; l8[j] = l;
      }
      const int off = ((b * 400 + mi) * 2 + c0) * 512 + lane * 8;
      *(bf16x8*)(Qh + off) = h8;
      *(bf16x8*)(Ql + off) = l8;
    }
  } else {                            // ---- V: RNE bf16, hi only
    const int gw = (x - 800) * 4 + w;
    const int b = gw / 200, rest = gw % 200;
    const int i = rest / 2, half = rest % 2;
    const float* vb = values + (size_t)b * 64 * NPIX;
    #pragma unroll
    for (int cc = 0; cc < 2; ++cc) {
      const int ct = 2 * half + cc;
      #pragma unroll
      for (int mh = 0; mh < 2; ++mh) {
        const float* vp = vb + (size_t)(16 * ct + l16) * NPIX + 64 * i + 32 * mh + 8 * qq;
        const float4 a  = *(const float4*)vp;
        const float4 b4 = *(const float4*)(vp + 4);
        const float t[8] = {a.x, a.y, a.z, a.w, b4.x, b4.y, b4.z, b4.w};
        bf16x8 h8;
        #pragma unroll
        for (int j = 0; j < 8; ++j) h8[j] = rne_bf16(t[j]);
        const int off = (((b * 100 + i) * 8) + ct * 2 + mh) * 512 + lane * 8;
        *(bf16x8*)(Vh + off) = h8;
      }
    }
  }
}

// ---------------- main: 400 blocks x 512 thr; 8-wave in-block m-split -------
__global__ __launch_bounds__(512, 4) void attn_main(
    const short* __restrict__ ws, float* __restrict__ out)
{
  const int tid  = threadIdx.x;
  const int w    = tid >> 6;          // wave 0..7 = m-eighth
  const int lane = tid & 63;
  const int l16  = lane & 15, qq = lane >> 4;
  const int x = blockIdx.x;
  const int b      = x & 3;           // batch -> XCDs {b, b+4}; KV 2.4MB < L2
  const int rowjob = x >> 2;          // 0..99
  const int rb     = rowjob * 64;

  const short* Qh = ws;
  const short* Kh = ws + 2 * SZ;
  const short* Vh = ws + 4 * SZ;
  float* ob = out + (size_t)b * 64 * NPIX;

  // LDS: loop — per-wave P (8 x 4 KB) + shared Q-lo (8 KB) = 40 KB;
  // combine — OC [64][65] f32 (16640 B, aliases P) + LST (2 KB at 40960).
  __shared__ char smem[43008];
  short* P   = ((short*)smem) + (w << 11);   // wave-private 2048 shorts
  short* QL  = ((short*)smem) + 16384;       // shared Q-lo frags (8 KB)
  float* OC  = (float*)smem;
  float* LST = (float*)(smem + 40960);       // [8 waves][4 strips][16]

  bf16x8 qfh[4][2];
  {
    const short* qp = Qh + (size_t)((b * 400 + rowjob * 4) * 2) * 512 + lane * 8;
    #pragma unroll
    for (int s = 0; s < 4; ++s)
      #pragma unroll
      for (int c0 = 0; c0 < 2; ++c0) {
        qfh[s][c0] = *(const bf16x8*)(qp + (s * 2 + c0) * 512);
        *(bf16x8*)(QL + ((s * 2 + c0) * 64 + lane) * 8) =
            *(const bf16x8*)(qp + SZ + (s * 2 + c0) * 512);   // 8x redundant, benign
      }
  }
  __syncthreads();

  f32x4 zero4 = {0.f, 0.f, 0.f, 0.f};
  f32x4 oacc[4][4];
  f32x4 lacc[4];
  #pragma unroll
  for (int ct = 0; ct < 4; ++ct)
    #pragma unroll
    for (int s = 0; s < 4; ++s) oacc[ct][s] = zero4;
  #pragma unroll
  for (int s = 0; s < 4; ++s) lacc[s] = zero4;

  bf16x8 onesA;
  #pragma unroll
  for (int j = 0; j < 8; ++j) onesA[j] = (short)0x3F80;

  bf16x8 kfh[2][2], kfl[2][2];
  bf16x8 vfh[4];

  auto loadK = [&](int i2) {
    const short* kp = Kh + (size_t)((b * 400 + 2 * i2) * 2) * 512 + lane * 8;
    #pragma unroll
    for (int mt = 0; mt < 2; ++mt)
      #pragma unroll
      for (int c0 = 0; c0 < 2; ++c0) {
        kfh[mt][c0] = *(const bf16x8*)(kp + (mt * 2 + c0) * 512);
        kfl[mt][c0] = *(const bf16x8*)(kp + SZ + (mt * 2 + c0) * 512);
      }
  };
  auto loadV = [&](int i2) {
    const short* vp = Vh + (size_t)((b * 100 + (i2 >> 1)) * 8) * 512 + lane * 8;
    #pragma unroll
    for (int ct = 0; ct < 4; ++ct)
      vfh[ct] = *(const bf16x8*)(vp + (ct * 2 + (i2 & 1)) * 512);
  };

  // wave w owns m-chunks [25w, 25w+25) of 32 m each
  const int i0 = w * 25;
  loadK(i0);
  loadV(i0);

  for (int it = 0; it < 25; ++it) {
    const int i2 = i0 + it;
    const int inext = (it == 24) ? i0 : i2 + 1;

    // ---- all strips' S-MFMAs first (4 independent chains)
    f32x4 a0[4], a1[4];
    #pragma unroll
    for (int s = 0; s < 4; ++s) {
      f32x4 t0 = zero4, t1 = zero4;
      #pragma unroll
      for (int c0 = 0; c0 < 2; ++c0) {
        const bf16x8 ql = *(const bf16x8*)(QL + ((s * 2 + c0) * 64 + lane) * 8);
        t0 = __builtin_amdgcn_mfma_f32_16x16x32_bf16(kfh[0][c0], qfh[s][c0], t0, 0, 0, 0);
        t0 = __builtin_amdgcn_mfma_f32_16x16x32_bf16(kfh[0][c0], ql,         t0, 0, 0, 0);
        t0 = __builtin_amdgcn_mfma_f32_16x16x32_bf16(kfl[0][c0], qfh[s][c0], t0, 0, 0, 0);
        t1 = __builtin_amdgcn_mfma_f32_16x16x32_bf16(kfh[1][c0], qfh[s][c0], t1, 0, 0, 0);
        t1 = __builtin_amdgcn_mfma_f32_16x16x32_bf16(kfh[1][c0], ql,         t1, 0, 0, 0);
        t1 = __builtin_amdgcn_mfma_f32_16x16x32_bf16(kfl[1][c0], qfh[s][c0], t1, 0, 0, 0);
      }
      a0[s] = t0; a1[s] = t1;
    }

    SCHED_FENCE();
    loadK(inext);
    SCHED_FENCE();

    // ---- softmax: exp2 + packed RNE, P hi-only
    #pragma unroll
    for (int s = 0; s < 4; ++s) {
      float p0 = EXP2(a0[s][0] - SHIFT2), p1 = EXP2(a0[s][1] - SHIFT2);
      float p2 = EXP2(a0[s][2] - SHIFT2), p3 = EXP2(a0[s][3] - SHIFT2);
      float p4 = EXP2(a1[s][0] - SHIFT2), p5 = EXP2(a1[s][1] - SHIFT2);
      float p6 = EXP2(a1[s][2] - SHIFT2), p7 = EXP2(a1[s][3] - SHIFT2);
      union { unsigned u[2]; short4 s4; } ua, ub;
      ua.u[0] = pk2(p0, p1); ua.u[1] = pk2(p2, p3);
      ub.u[0] = pk2(p4, p5); ub.u[1] = pk2(p6, p7);
      const int gbase = (s * 4 + (qq >> 1)) * 16 + l16;
      *(short4*)(P + (gbase * 8 + 4 * (qq & 1))) = ua.s4;
      *(short4*)(P + ((gbase + 32) * 8 + 4 * (qq & 1))) = ub.s4;
    }

    bf16x8 pf[4];
    #pragma unroll
    for (int s = 0; s < 4; ++s)
      pf[s] = *(const bf16x8*)(P + (((s * 4 + qq) * 16 + l16) * 8));

    // ---- O^T += Vh * P^T ; l += 1 * P
    #pragma unroll
    for (int ct = 0; ct < 4; ++ct)
      #pragma unroll
      for (int s = 0; s < 4; ++s)
        oacc[ct][s] = __builtin_amdgcn_mfma_f32_16x16x32_bf16(vfh[ct], pf[s], oacc[ct][s], 0, 0, 0);
    #pragma unroll
    for (int s = 0; s < 4; ++s)
      lacc[s] = __builtin_amdgcn_mfma_f32_16x16x32_bf16(onesA, pf[s], lacc[s], 0, 0, 0);

    SCHED_FENCE();
    loadV(inext);
    SCHED_FENCE();
  }

  // ---------------- in-block combine across the 8 m-eighths -----------------
  if (qq == 0) {
    #pragma unroll
    for (int s = 0; s < 4; ++s) LST[w * 64 + s * 16 + l16] = lacc[s][0];
  }
  __syncthreads();    // loop done; P region free for OC

  #pragma unroll
  for (int wp = 0; wp < 8; ++wp) {
    if (w == wp) {
      #pragma unroll
      for (int ct = 0; ct < 4; ++ct)
        #pragma unroll
        for (int s = 0; s < 4; ++s)
          #pragma unroll
          for (int r = 0; r < 4; ++r) {
            const int c = 16 * ct + 4 * qq + r;
            const int idx = c * 65 + 16 * s + l16;
            if (wp == 0) OC[idx] = oacc[ct][s][r];
            else         OC[idx] += oacc[ct][s][r];
          }
    }
    __syncthreads();
  }

  // final scale + coalesced store: 512 threads, 8 channels each
  {
    const int r  = tid & 63;
    const int cg = tid >> 6;          // 0..7
    float lsum = 0.f;
    #pragma unroll
    for (int w2 = 0; w2 < 8; ++w2)
      lsum += LST[w2 * 64 + (r >> 4) * 16 + (r & 15)];
    const float inv = 1.0f / lsum;
    #pragma unroll
    for (int u = 0; u < 8; ++u) {
      const int c = cg * 8 + u;
      ob[(size_t)c * NPIX + rb + r] = OC[c * 65 + r] * inv;
    }
  }
}

extern "C" void kernel_launch(void* const* d_in, const int* in_sizes, int n_in,
                              void* d_out, int out_size, void* d_ws, size_t ws_size,
                              hipStream_t stream) {
  const float* query  = (const float*)d_in[0];
  const float* keys   = (const float*)d_in[1];
  const float* values = (const float*)d_in[2];
  const float* Wq     = (const float*)d_in[3];
  const float* bq     = (const float*)d_in[4];
  short* ws = (short*)d_ws;           // 5*SZ*2 = 16.4 MB
  prep<<<dim3(1000), dim3(256), 0, stream>>>(query, keys, values, Wq, bq, ws);
  attn_main<<<dim3(400), dim3(512), 0, stream>>>(ws, (float*)d_out);
}

// Round 13
// 182.632 us; speedup vs baseline: 2.8164x; 2.8164x over previous
//
#include <hip/hip_runtime.h>
#include <hip/hip_bf16.h>

// CostAttention on MI355X — round 13 (= R12 with launch_bounds fix).
// R12 post-mortem: VGPR_Count=64 + 903 MB WRITE = catastrophic scratch spill.
// __launch_bounds__ 2nd arg is min BLOCKS per CU (CUDA semantics), NOT waves
// per EU: (512,4) -> 4 blk x 8 waves = 8 waves/SIMD -> 512/8 = 64-VGPR cap,
// exactly what the compiler emitted. Fix: (512,1) -> 2 waves/SIMD -> 256 cap.
// Structure unchanged: 400 blocks x 512 thr (8 waves), block = one 64-row
// job, m-split over 8 waves (25 chunks of 32 m), in-block LDS combine only.
// Keep: V-lo dropped, fixed-shift exp2 softmax, P-hi-only RNE, ones-MFMA l,
// cross-iter K/V prefetch, R11 prep.
//
// ws layout: shorts [Qh][Ql][Kh][Kl][Vh], each SZ = 1,638,400 shorts (16.4MB).
//   Q/K chunk  ((b*400+mi)*2+c0)*512 + lane*8 : elem [r=16mi+l16][c=32c0+8qq+j]
//   V   chunk  (((b*100+i64)*8)+ct*2+mh)*512 + lane*8 : elem [c=16ct+l16][m=64i64+32mh+8qq+j]

#define NPIX 6400
#define SZ 1638400
#define SHIFT2 11.541560327111707f   // 8 * log2(e)

typedef float f32x4 __attribute__((ext_vector_type(4)));
typedef short bf16x8 __attribute__((ext_vector_type(8)));

#if defined(__has_builtin)
#if __has_builtin(__builtin_amdgcn_sched_barrier)
#define SCHED_FENCE() __builtin_amdgcn_sched_barrier(0)
#endif
#if __has_builtin(__builtin_amdgcn_exp2f)
#define EXP2(x) __builtin_amdgcn_exp2f(x)
#endif
#endif
#ifndef SCHED_FENCE
#define SCHED_FENCE()
#endif
#ifndef EXP2
#define EXP2(x) exp2f(x)
#endif

__device__ __forceinline__ void split2(float x, short& h, short& l) {
  unsigned xb = __float_as_uint(x);
  h = (short)(xb >> 16);
  float r = x - __uint_as_float(xb & 0xffff0000u);
  l = (short)(__float_as_uint(r) >> 16);
}

__device__ __forceinline__ short rne_bf16(float x) {
  unsigned u = __float_as_uint(x);
  return (short)((u + 0x7fffu + ((u >> 16) & 1u)) >> 16);
}

__device__ __forceinline__ unsigned pk2(float a, float b) {
  __hip_bfloat162 t = __float22bfloat162_rn(make_float2(a, b));
  unsigned r;
  __builtin_memcpy(&r, &t, 4);
  return r;
}

// ---------------- prep (unchanged): stage -> LDS -> frag gather -------------
// grid 1000: [0,400) K (b,m-tile) | [400,800) Q-proj (b,r-tile) | [800,1000) V
__global__ __launch_bounds__(256, 2) void prep(
    const float* __restrict__ query, const float* __restrict__ keys,
    const float* __restrict__ values, const float* __restrict__ Wq,
    const float* __restrict__ bq, short* __restrict__ ws)
{
  const int tid = threadIdx.x;
  const int w = tid >> 6;
  const int lane = tid & 63, l16 = lane & 15, qq = lane >> 4;
  short* Qh = ws;          short* Ql = ws + SZ;
  short* Kh = ws + 2 * SZ; short* Kl = ws + 3 * SZ;
  short* Vh = ws + 4 * SZ;
  const int x = blockIdx.x;

  __shared__ float T[64 * 65];

  if (x < 400) {                      // ---- K split (trunc hi/lo, 3-term S)
    const int b = x / 100, t64 = x % 100;
    const int m0 = t64 * 64;
    const float* kb = keys + (size_t)b * 64 * NPIX;
    {
      const int ch = tid >> 2, ml = (tid & 3) * 4;
      const float* src = kb + (size_t)ch * NPIX + m0 + ml;
      #pragma unroll
      for (int u = 0; u < 4; ++u)
        *(float4*)&T[ch * 65 + ml + 16 * u] = *(const float4*)(src + 16 * u);
    }
    __syncthreads();
    const int mi = t64 * 4 + w;
    #pragma unroll
    for (int c0 = 0; c0 < 2; ++c0) {
      float t[8];
      #pragma unroll
      for (int j = 0; j < 8; ++j)
        t[j] = T[(32 * c0 + 8 * qq + j) * 65 + 16 * w + l16];
      bf16x8 h8, l8;
      #pragma unroll
      for (int j = 0; j < 8; ++j) { short h, l; split2(t[j], h, l); h8[j] = h; l8[j] = l; }
      const int off = ((b * 400 + mi) * 2 + c0) * 512 + lane * 8;
      *(bf16x8*)(Kh + off) = h8;
      *(bf16x8*)(Kl + off) = l8;
    }
  } else if (x < 800) {               // ---- Q projection + trunc hi/lo split
    const int y = x - 400;
    const int b = y / 100, t64 = y % 100;
    const int r0 = t64 * 64;
    const float* qb = query + (size_t)b * 64 * NPIX;
    {
      const int ch = tid >> 2, ml = (tid & 3) * 4;
      const float* src = qb + (size_t)ch * NPIX + r0 + ml;
      #pragma unroll
      for (int u = 0; u < 4; ++u)
        *(float4*)&T[ch * 65 + ml + 16 * u] = *(const float4*)(src + 16 * u);
    }
    __syncthreads();
    const int mi = t64 * 4 + w;

    float acc[2][8];
    #pragma unroll
    for (int c0 = 0; c0 < 2; ++c0)
      #pragma unroll
      for (int j = 0; j < 8; ++j) acc[c0][j] = 0.f;

    for (int cin4 = 0; cin4 < 64; cin4 += 4) {
      float xv[4];
      #pragma unroll
      for (int u = 0; u < 4; ++u)
        xv[u] = T[(cin4 + u) * 65 + 16 * w + l16];
      #pragma unroll
      for (int c0 = 0; c0 < 2; ++c0)
        #pragma unroll
        for (int j = 0; j < 8; ++j) {
          const float4 wv = *(const float4*)&Wq[(32 * c0 + 8 * qq + j) * 64 + cin4];
          acc[c0][j] += wv.x * xv[0] + wv.y * xv[1] + wv.z * xv[2] + wv.w * xv[3];
        }
    }
    #pragma unroll
    for (int c0 = 0; c0 < 2; ++c0) {
      bf16x8 h8, l8;
      #pragma unroll
      for (int j = 0; j < 8; ++j) {
        // scale = (1/8)*log2(e): S in log2 domain -> raw exp2 in main
        float v = (acc[c0][j] + bq[32 * c0 + 8 * qq + j]) * 0.18033688011112042f;
        short h, l; split2(v, h, l);
        h8[j] = h; l8[j] = l;
      }
      const int off = ((b * 400 + mi) * 2 + c0) * 512 + lane * 8;
      *(bf16x8*)(Qh + off) = h8;
      *(bf16x8*)(Ql + off) = l8;
    }
  } else {                            // ---- V: RNE bf16, hi only
    const int gw = (x - 800) * 4 + w;
    const int b = gw / 200, rest = gw % 200;
    const int i = rest / 2, half = rest % 2;
    const float* vb = values + (size_t)b * 64 * NPIX;
    #pragma unroll
    for (int cc = 0; cc < 2; ++cc) {
      const int ct = 2 * half + cc;
      #pragma unroll
      for (int mh = 0; mh < 2; ++mh) {
        const float* vp = vb + (size_t)(16 * ct + l16) * NPIX + 64 * i + 32 * mh + 8 * qq;
        const float4 a  = *(const float4*)vp;
        const float4 b4 = *(const float4*)(vp + 4);
        const float t[8] = {a.x, a.y, a.z, a.w, b4.x, b4.y, b4.z, b4.w};
        bf16x8 h8;
        #pragma unroll
        for (int j = 0; j < 8; ++j) h8[j] = rne_bf16(t[j]);
        const int off = (((b * 100 + i) * 8) + ct * 2 + mh) * 512 + lane * 8;
        *(bf16x8*)(Vh + off) = h8;
      }
    }
  }
}

// ---------------- main: 400 blocks x 512 thr; 8-wave in-block m-split -------
// (512,1): 1 block/CU -> 8 waves/CU -> 2 waves/SIMD -> 256-VGPR cap, no spill.
__global__ __launch_bounds__(512, 1) void attn_main(
    const short* __restrict__ ws, float* __restrict__ out)
{
  const int tid  = threadIdx.x;
  const int w    = tid >> 6;          // wave 0..7 = m-eighth
  const int lane = tid & 63;
  const int l16  = lane & 15, qq = lane >> 4;
  const int x = blockIdx.x;
  const int b      = x & 3;           // batch -> XCDs {b, b+4}; KV 2.4MB < L2
  const int rowjob = x >> 2;          // 0..99
  const int rb     = rowjob * 64;

  const short* Qh = ws;
  const short* Kh = ws + 2 * SZ;
  const short* Vh = ws + 4 * SZ;
  float* ob = out + (size_t)b * 64 * NPIX;

  // LDS: loop — per-wave P (8 x 4 KB) + shared Q-lo (8 KB) = 40 KB;
  // combine — OC [64][65] f32 (16640 B, aliases P) + LST (2 KB at 40960).
  __shared__ char smem[43008];
  short* P   = ((short*)smem) + (w << 11);   // wave-private 2048 shorts
  short* QL  = ((short*)smem) + 16384;       // shared Q-lo frags (8 KB)
  float* OC  = (float*)smem;
  float* LST = (float*)(smem + 40960);       // [8 waves][4 strips][16]

  bf16x8 qfh[4][2];
  {
    const short* qp = Qh + (size_t)((b * 400 + rowjob * 4) * 2) * 512 + lane * 8;
    #pragma unroll
    for (int s = 0; s < 4; ++s)
      #pragma unroll
      for (int c0 = 0; c0 < 2; ++c0) {
        qfh[s][c0] = *(const bf16x8*)(qp + (s * 2 + c0) * 512);
        *(bf16x8*)(QL + ((s * 2 + c0) * 64 + lane) * 8) =
            *(const bf16x8*)(qp + SZ + (s * 2 + c0) * 512);   // 8x redundant, benign
      }
  }
  __syncthreads();

  f32x4 zero4 = {0.f, 0.f, 0.f, 0.f};
  f32x4 oacc[4][4];
  f32x4 lacc[4];
  #pragma unroll
  for (int ct = 0; ct < 4; ++ct)
    #pragma unroll
    for (int s = 0; s < 4; ++s) oacc[ct][s] = zero4;
  #pragma unroll
  for (int s = 0; s < 4; ++s) lacc[s] = zero4;

  bf16x8 onesA;
  #pragma unroll
  for (int j = 0; j < 8; ++j) onesA[j] = (short)0x3F80;

  bf16x8 kfh[2][2], kfl[2][2];
  bf16x8 vfh[4];

  auto loadK = [&](int i2) {
    const short* kp = Kh + (size_t)((b * 400 + 2 * i2) * 2) * 512 + lane * 8;
    #pragma unroll
    for (int mt = 0; mt < 2; ++mt)
      #pragma unroll
      for (int c0 = 0; c0 < 2; ++c0) {
        kfh[mt][c0] = *(const bf16x8*)(kp + (mt * 2 + c0) * 512);
        kfl[mt][c0] = *(const bf16x8*)(kp + SZ + (mt * 2 + c0) * 512);
      }
  };
  auto loadV = [&](int i2) {
    const short* vp = Vh + (size_t)((b * 100 + (i2 >> 1)) * 8) * 512 + lane * 8;
    #pragma unroll
    for (int ct = 0; ct < 4; ++ct)
      vfh[ct] = *(const bf16x8*)(vp + (ct * 2 + (i2 & 1)) * 512);
  };

  // wave w owns m-chunks [25w, 25w+25) of 32 m each
  const int i0 = w * 25;
  loadK(i0);
  loadV(i0);

  for (int it = 0; it < 25; ++it) {
    const int i2 = i0 + it;
    const int inext = (it == 24) ? i0 : i2 + 1;

    // ---- all strips' S-MFMAs first (4 independent chains)
    f32x4 a0[4], a1[4];
    #pragma unroll
    for (int s = 0; s < 4; ++s) {
      f32x4 t0 = zero4, t1 = zero4;
      #pragma unroll
      for (int c0 = 0; c0 < 2; ++c0) {
        const bf16x8 ql = *(const bf16x8*)(QL + ((s * 2 + c0) * 64 + lane) * 8);
        t0 = __builtin_amdgcn_mfma_f32_16x16x32_bf16(kfh[0][c0], qfh[s][c0], t0, 0, 0, 0);
        t0 = __builtin_amdgcn_mfma_f32_16x16x32_bf16(kfh[0][c0], ql,         t0, 0, 0, 0);
        t0 = __builtin_amdgcn_mfma_f32_16x16x32_bf16(kfl[0][c0], qfh[s][c0], t0, 0, 0, 0);
        t1 = __builtin_amdgcn_mfma_f32_16x16x32_bf16(kfh[1][c0], qfh[s][c0], t1, 0, 0, 0);
        t1 = __builtin_amdgcn_mfma_f32_16x16x32_bf16(kfh[1][c0], ql,         t1, 0, 0, 0);
        t1 = __builtin_amdgcn_mfma_f32_16x16x32_bf16(kfl[1][c0], qfh[s][c0], t1, 0, 0, 0);
      }
      a0[s] = t0; a1[s] = t1;
    }

    SCHED_FENCE();
    loadK(inext);
    SCHED_FENCE();

    // ---- softmax: exp2 + packed RNE, P hi-only
    #pragma unroll
    for (int s = 0; s < 4; ++s) {
      float p0 = EXP2(a0[s][0] - SHIFT2), p1 = EXP2(a0[s][1] - SHIFT2);
      float p2 = EXP2(a0[s][2] - SHIFT2), p3 = EXP2(a0[s][3] - SHIFT2);
      float p4 = EXP2(a1[s][0] - SHIFT2), p5 = EXP2(a1[s][1] - SHIFT2);
      float p6 = EXP2(a1[s][2] - SHIFT2), p7 = EXP2(a1[s][3] - SHIFT2);
      union { unsigned u[2]; short4 s4; } ua, ub;
      ua.u[0] = pk2(p0, p1); ua.u[1] = pk2(p2, p3);
      ub.u[0] = pk2(p4, p5); ub.u[1] = pk2(p6, p7);
      const int gbase = (s * 4 + (qq >> 1)) * 16 + l16;
      *(short4*)(P + (gbase * 8 + 4 * (qq & 1))) = ua.s4;
      *(short4*)(P + ((gbase + 32) * 8 + 4 * (qq & 1))) = ub.s4;
    }

    bf16x8 pf[4];
    #pragma unroll
    for (int s = 0; s < 4; ++s)
      pf[s] = *(const bf16x8*)(P + (((s * 4 + qq) * 16 + l16) * 8));

    // ---- O^T += Vh * P^T ; l += 1 * P
    #pragma unroll
    for (int ct = 0; ct < 4; ++ct)
      #pragma unroll
      for (int s = 0; s < 4; ++s)
        oacc[ct][s] = __builtin_amdgcn_mfma_f32_16x16x32_bf16(vfh[ct], pf[s], oacc[ct][s], 0, 0, 0);
    #pragma unroll
    for (int s = 0; s < 4; ++s)
      lacc[s] = __builtin_amdgcn_mfma_f32_16x16x32_bf16(onesA, pf[s], lacc[s], 0, 0, 0);

    SCHED_FENCE();
    loadV(inext);
    SCHED_FENCE();
  }

  // ---------------- in-block combine across the 8 m-eighths -----------------
  if (qq == 0) {
    #pragma unroll
    for (int s = 0; s < 4; ++s) LST[w * 64 + s * 16 + l16] = lacc[s][0];
  }
  __syncthreads();    // loop done; P region free for OC

  #pragma unroll
  for (int wp = 0; wp < 8; ++wp) {
    if (w == wp) {
      #pragma unroll
      for (int ct = 0; ct < 4; ++ct)
        #pragma unroll
        for (int s = 0; s < 4; ++s)
          #pragma unroll
          for (int r = 0; r < 4; ++r) {
            const int c = 16 * ct + 4 * qq + r;
            const int idx = c * 65 + 16 * s + l16;
            if (wp == 0) OC[idx] = oacc[ct][s][r];
            else         OC[idx] += oacc[ct][s][r];
          }
    }
    __syncthreads();
  }

  // final scale + coalesced store: 512 threads, 8 channels each
  {
    const int r  = tid & 63;
    const int cg = tid >> 6;          // 0..7
    float lsum = 0.f;
    #pragma unroll
    for (int w2 = 0; w2 < 8; ++w2)
      lsum += LST[w2 * 64 + (r >> 4) * 16 + (r & 15)];
    const float inv = 1.0f / lsum;
    #pragma unroll
    for (int u = 0; u < 8; ++u) {
      const int c = cg * 8 + u;
      ob[(size_t)c * NPIX + rb + r] = OC[c * 65 + r] * inv;
    }
  }
}

extern "C" void kernel_launch(void* const* d_in, const int* in_sizes, int n_in,
                              void* d_out, int out_size, void* d_ws, size_t ws_size,
                              hipStream_t stream) {
  const float* query  = (const float*)d_in[0];
  const float* keys   = (const float*)d_in[1];
  const float* values = (const float*)d_in[2];
  const float* Wq     = (const float*)d_in[3];
  const float* bq     = (const float*)d_in[4];
  short* ws = (short*)d_ws;           // 5*SZ*2 = 16.4 MB
  prep<<<dim3(1000), dim3(256), 0, stream>>>(query, keys, values, Wq, bq, ws);
  attn_main<<<dim3(400), dim3(512), 0, stream>>>(ws, (float*)d_out);
}